// Round 9
// baseline (5797.941 us; speedup 1.0000x reference)
//
#include <hip/hip_runtime.h>
#include <stdint.h>

// ResRnn persistent kernel. R9: TWO independent chains per CU.
//  - 4 groups x 32 rows, but 128 N-chunks of 16 cols -> 512 WGs, 2 per CU
//    (__launch_bounds__(256,2): 8 waves/CU at <=256 regs; weights now only
//    128 VGPRs: B1[16]+B2[16] short8). group = bid>>7 so co-resident WGs are
//    from DIFFERENT groups: one chain's handoff wait is hidden by the other
//    chain's compute (R8 evidence: 4 waves/CU, 92% idle, L2 serves 97% of
//    exchange -> latency-bound, needs overlap not bandwidth).
//  - Exchange machinery unchanged from R8 (proven): relaxed agent sc1
//    write-through stores, LLC-direct loads, per-wave 16B flags, detect-once
//    window wait (now 2 polls/lane over a 32-chunk x 4-wave window),
//    ping-pong buffers (safety: each WG's 4 wave-windows tile ALL chunks, so
//    the R8 transitivity proof carries over).

#define NSTEPS 128
#define NB 128
#define WID 2048
#define SS 1984

#define SFN (128 * 1984)   // floats per Sf slot
#define SBN (128 * 1984)   // shorts per Sb slot
#define HN  (128 * 2048)   // shorts per h slot

typedef __attribute__((ext_vector_type(8))) short short8;
typedef __attribute__((ext_vector_type(4))) float f32x4;
typedef unsigned long long u64;

static __device__ __forceinline__ short f2bf(float f) {
  union { float f; unsigned u; } v; v.f = f;
  unsigned r = (v.u + 0x7fffu + ((v.u >> 16) & 1u)) >> 16;  // RNE
  return (short)r;
}
static __device__ __forceinline__ short8 pack8(f32x4 lo, f32x4 hi) {
  short8 r;
  r[0] = f2bf(lo[0]); r[1] = f2bf(lo[1]); r[2] = f2bf(lo[2]); r[3] = f2bf(lo[3]);
  r[4] = f2bf(hi[0]); r[5] = f2bf(hi[1]); r[6] = f2bf(hi[2]); r[7] = f2bf(hi[3]);
  return r;
}
static __device__ __forceinline__ void ast64(void* p, u64 v) {
  __hip_atomic_store((u64*)p, v, __ATOMIC_RELAXED, __HIP_MEMORY_SCOPE_AGENT);
}
static __device__ __forceinline__ void ast32(unsigned* p, unsigned v) {
  __hip_atomic_store(p, v, __ATOMIC_RELAXED, __HIP_MEMORY_SCOPE_AGENT);
}
static __device__ __forceinline__ u64 ald64(const void* p) {
  return __hip_atomic_load((const u64*)p, __ATOMIC_RELAXED, __HIP_MEMORY_SCOPE_AGENT);
}
static __device__ __forceinline__ unsigned ald32(const unsigned* p) {
  return __hip_atomic_load(p, __ATOMIC_RELAXED, __HIP_MEMORY_SCOPE_AGENT);
}
static __device__ __forceinline__ short8 ald_s8(const void* p) {
  union { u64 u[2]; short8 s; } r;
  r.u[0] = ald64((const char*)p); r.u[1] = ald64((const char*)p + 8);
  return r.s;
}

__global__ __launch_bounds__(256, 2)
void resrnn_kernel(const float* __restrict__ inp, const float* __restrict__ W1,
                   const float* __restrict__ b1f, const float* __restrict__ W2,
                   const float* __restrict__ b2f, float* __restrict__ out,
                   unsigned char* __restrict__ ws)
{
  const int tid   = threadIdx.x;
  const int bid   = blockIdx.x;
  const int group = bid >> 7;        // 4 groups of 32 rows; co-resident CUs mix groups
  const int chunk = bid & 127;       // 128 N-chunks of 16 cols
  const int mbase = group * 32;
  const int n0    = chunk * 16;
  const int wave  = tid >> 6;
  const int lane  = tid & 63;
  const int l15   = lane & 15;
  const int q8    = (lane >> 4) * 8;
  const int kb    = wave * 512;

  // per-group flag arrays: slot (c*4 + producer_wave) x 16B, monotone gen.
  unsigned* sflags = (unsigned*)(ws + group * 16384);          // S ready (chunks 0..123)
  unsigned* hflags = (unsigned*)(ws + group * 16384 + 8192);   // h ready (chunks 0..127)
  float* SfR = (float*)(ws + 65536);
  short* SbR = (short*)(ws + 65536 + (size_t)2 * SFN * 4);
  short* hbR = (short*)(ws + 65536 + (size_t)2 * SFN * 4 + (size_t)2 * SBN * 2);

  __shared__ float red1[4][8][65];
  __shared__ float red2[4][8][65];

  // ---- one-time: weight B-fragments into registers (128 VGPRs total) ----
  short8 B1[16], B2[16];
#pragma unroll
  for (int ks = 0; ks < 16; ++ks) {
    const float* p1 = W1 + (size_t)(n0 + l15) * WID + (kb + ks * 32 + q8);
    B1[ks] = pack8(*(const f32x4*)p1, *(const f32x4*)(p1 + 4));
    const float* p2 = W2 + (size_t)(n0 + l15) * WID + (kb + ks * 32 + q8);
    B2[ks] = pack8(*(const f32x4*)p2, *(const f32x4*)(p2 + 4));
  }

  const int m0 = mbase + l15;        // A rows 0-15 of group
  const int m1 = mbase + 16 + l15;   // A rows 16-31
  const int o    = tid * 2;          // epilogue: 2 outputs/thread of the 32x16 tile
  const int ml   = o >> 4;           // row 0..31  (wave w owns rows 8w..8w+7)
  const int nl   = o & 15;           // col pair base (even)
  const int mrow = mbase + ml;
  const int lidx0 = ((ml & 15) >> 2) * 16 + nl;      // C-frag lane for (ml, nl)
  const int ridx  = (ml >> 4) * 4 + (ml & 3);        // C-frag reg row
  const float b1a = b1f[n0 + nl], b1b = b1f[n0 + nl + 1];
  const float b2a = b2f[n0 + nl], b2b = b2f[n0 + nl + 1];

  // poll slots (2 per lane): phase1 wave-w window = S slots [128w-16, 128w+112)
  const int i2  = lane * 2;
  const int s1a = 128 * wave - 16 + i2;              // slot = chunk*4 + wave
  const bool v1a = (s1a >= 0) && (s1a < 496);        // S chunks 0..123 only
  const bool v1b = (s1a + 1 >= 0) && (s1a + 1 < 496);
  const unsigned* p1a = sflags + (v1a ? s1a : 0) * 4;
  const unsigned* p1b = sflags + (v1b ? (s1a + 1) : 0) * 4;
  const unsigned* p2a = hflags + (128 * wave + i2) * 4;        // h chunks 32w..32w+31
  const unsigned* p2b = hflags + (128 * wave + i2 + 1) * 4;

#pragma unroll 1
  for (int t = 0; t < NSTEPS; ++t) {
    const int sW = t & 1;
    const int sR = sW ^ 1;
    float*       SfNew = SfR + (size_t)sW * SFN;
    const float* SfOld = SfR + (size_t)sR * SFN;
    const short* SbOld = SbR + (size_t)sR * SBN;
    short*       SbNew = SbR + (size_t)sW * SBN;
    short*       hb    = hbR + (size_t)sW * HN;

    // ============ phase 1: u = s@W1^T ; h = |u+b1| ============
    if (t > 0) {                      // detect-once: whole 32-chunk x 4-wave window
      const unsigned tgt = (unsigned)t;
      for (;;) {
        unsigned va = v1a ? ald32(p1a) : tgt;
        unsigned vb = v1b ? ald32(p1b) : tgt;
        unsigned mn = va < vb ? va : vb;
        if (__ballot(mn >= tgt) == ~0ull) break;
        __builtin_amdgcn_s_sleep(1);
      }
    }
    f32x4 a00{}, a10{};
#pragma unroll
    for (int ks = 0; ks < 16; ++ks) {                // loads stream ungated
      if (kb == 0 && ks < 2) {
        const float* p0 = inp + ((size_t)t * NB + m0) * 64 + (ks * 32 + q8);
        const float* p1 = inp + ((size_t)t * NB + m1) * 64 + (ks * 32 + q8);
        short8 x0 = pack8(*(const f32x4*)p0, *(const f32x4*)(p0 + 4));
        short8 x1 = pack8(*(const f32x4*)p1, *(const f32x4*)(p1 + 4));
        a00 = __builtin_amdgcn_mfma_f32_16x16x32_bf16(x0, B1[ks], a00, 0, 0, 0);
        a10 = __builtin_amdgcn_mfma_f32_16x16x32_bf16(x1, B1[ks], a10, 0, 0, 0);
      } else if (t > 0) {
        short8 x0 = ald_s8(SbOld + (size_t)m0 * SS + (kb + ks * 32 - 64 + q8));
        short8 x1 = ald_s8(SbOld + (size_t)m1 * SS + (kb + ks * 32 - 64 + q8));
        a00 = __builtin_amdgcn_mfma_f32_16x16x32_bf16(x0, B1[ks], a00, 0, 0, 0);
        a10 = __builtin_amdgcn_mfma_f32_16x16x32_bf16(x1, B1[ks], a10, 0, 0, 0);
      }
    }
#pragma unroll
    for (int r = 0; r < 4; ++r) {
      red1[wave][r][lane]     = a00[r];     // rows 0-15
      red1[wave][4 + r][lane] = a10[r];     // rows 16-31
    }
    __syncthreads();   // gates epilogue behind the WG-wide union of S-waits
    {
      float s0 = red1[0][ridx][lidx0]     + red1[1][ridx][lidx0]
               + red1[2][ridx][lidx0]     + red1[3][ridx][lidx0] + b1a;
      float s1 = red1[0][ridx][lidx0 + 1] + red1[1][ridx][lidx0 + 1]
               + red1[2][ridx][lidx0 + 1] + red1[3][ridx][lidx0 + 1] + b1b;
      unsigned hu = (unsigned)(unsigned short)f2bf(fabsf(s0))
                  | ((unsigned)(unsigned short)f2bf(fabsf(s1)) << 16);
      ast32((unsigned*)(hb + (size_t)mrow * WID + (n0 + nl)), hu);
    }
    asm volatile("s_waitcnt vmcnt(0)" ::: "memory");   // this wave's rows at LLC
    if (lane == 0)
      ast32(hflags + (chunk * 4 + wave) * 4, (unsigned)t + 1);

    // ============ phase 2: g = h@W2^T ; state update ============
    {
      const unsigned tgt = (unsigned)t + 1;
      for (;;) {
        unsigned va = ald32(p2a);
        unsigned vb = ald32(p2b);
        unsigned mn = va < vb ? va : vb;
        if (__ballot(mn >= tgt) == ~0ull) break;
        __builtin_amdgcn_s_sleep(1);
      }
    }
    f32x4 c00{}, c10{};
    {
      const short* h0 = hb + (size_t)m0 * WID + kb + q8;
      const short* h1 = hb + (size_t)m1 * WID + kb + q8;
#pragma unroll
      for (int ks = 0; ks < 16; ++ks) {              // loads stream ungated
        short8 x0 = ald_s8(h0 + ks * 32);
        short8 x1 = ald_s8(h1 + ks * 32);
        c00 = __builtin_amdgcn_mfma_f32_16x16x32_bf16(x0, B2[ks], c00, 0, 0, 0);
        c10 = __builtin_amdgcn_mfma_f32_16x16x32_bf16(x1, B2[ks], c10, 0, 0, 0);
      }
    }
#pragma unroll
    for (int r = 0; r < 4; ++r) {
      red2[wave][r][lane]     = c00[r];
      red2[wave][4 + r][lane] = c10[r];
    }
    __syncthreads();   // gates epilogue behind the WG-wide union of h-waits
    if (t < NSTEPS - 1) {
      if (n0 < SS) {   // chunks 124-127 are dropped by the shift (until final step)
        float g0 = red2[0][ridx][lidx0]     + red2[1][ridx][lidx0]
                 + red2[2][ridx][lidx0]     + red2[3][ridx][lidx0] + b2a;
        float g1 = red2[0][ridx][lidx0 + 1] + red2[1][ridx][lidx0 + 1]
                 + red2[2][ridx][lidx0 + 1] + red2[3][ridx][lidx0 + 1] + b2b;
        const int c0 = n0 + nl;
        float pv0, pv1;
        if (c0 < 64) {
          pv0 = inp[((size_t)t * NB + mrow) * 64 + c0];
          pv1 = inp[((size_t)t * NB + mrow) * 64 + c0 + 1];
        } else if (t > 0) {   // chunk c-4: covered by this WG's phase-1 window union
          union { u64 u; float f[2]; } pu;
          pu.u = ald64(SfOld + (size_t)mrow * SS + (c0 - 64));
          pv0 = pu.f[0]; pv1 = pu.f[1];
        } else { pv0 = 0.f; pv1 = 0.f; }
        float sv0 = 0.9f * pv0 + 0.1f * g0;
        float sv1 = 0.9f * pv1 + 0.1f * g1;
        union { float f[2]; u64 u; } su; su.f[0] = sv0; su.f[1] = sv1;
        ast64(SfNew + (size_t)mrow * SS + c0, su.u);
        unsigned sb = (unsigned)(unsigned short)f2bf(sv0)
                    | ((unsigned)(unsigned short)f2bf(sv1) << 16);
        ast32((unsigned*)(SbNew + (size_t)mrow * SS + c0), sb);
      }
      asm volatile("s_waitcnt vmcnt(0)" ::: "memory");
      if (lane == 0 && chunk < 124)
        ast32(sflags + (chunk * 4 + wave) * 4, (unsigned)t + 1);
    } else {
      if (n0 >= SS) {    // final step: chunks 124-127 produce out
        float g0 = red2[0][ridx][lidx0]     + red2[1][ridx][lidx0]
                 + red2[2][ridx][lidx0]     + red2[3][ridx][lidx0] + b2a;
        float g1 = red2[0][ridx][lidx0 + 1] + red2[1][ridx][lidx0 + 1]
                 + red2[2][ridx][lidx0 + 1] + red2[3][ridx][lidx0 + 1] + b2b;
        const int c0 = n0 + nl;
        union { u64 u; float f[2]; } pu;
        pu.u = ald64(SfOld + (size_t)mrow * SS + (c0 - 64));
        float* po = out + (size_t)mrow * 64 + (c0 - SS);
        po[0] = 0.9f * pu.f[0] + 0.1f * g0;
        po[1] = 0.9f * pu.f[1] + 0.1f * g1;
      }
    }
  }
}

extern "C" void kernel_launch(void* const* d_in, const int* in_sizes, int n_in,
                              void* d_out, int out_size, void* d_ws, size_t ws_size,
                              hipStream_t stream)
{
  (void)in_sizes; (void)n_in; (void)out_size; (void)ws_size;
  const float* inp = (const float*)d_in[0];
  const float* W1  = (const float*)d_in[1];
  const float* b1  = (const float*)d_in[2];
  const float* W2  = (const float*)d_in[3];
  const float* b2  = (const float*)d_in[4];
  float* out = (float*)d_out;

  hipMemsetAsync(d_ws, 0, 65536, stream);  // flag arrays
  resrnn_kernel<<<dim3(512), dim3(256), 0, stream>>>(
      inp, W1, b1, W2, b2, out, (unsigned char*)d_ws);
}

// Round 10
// 2661.291 us; speedup vs baseline: 2.1786x; 2.1786x over previous
//
#include <hip/hip_runtime.h>
#include <stdint.h>

// ResRnn R10: kernel-per-GEMM, graph-replayed.
// The hardware kernel boundary IS the barrier: dependent launches on one stream
// give a device-wide sync + automatic L2 release/acquire for ~2-3us -- cheaper
// than the best measured software handoff (~4.7us, R2..R8 all 2.4-2.8ms).
// 1 prepass (W fp32->bf16) + 128 x {gemm1, gemm2} = 257 launches, no atomics,
// no flags, plain cached loads/stores everywhere.
// Weights are streamed from LLC each launch (price of losing reg residency);
// mt = bid&3 => all 32 WGs of an XCD share one A M-slice (one L2 refill).

#define NSTEPS 128
#define NB 128
#define WID 2048
#define SS 1984

typedef __attribute__((ext_vector_type(8))) short short8;
typedef __attribute__((ext_vector_type(4))) short short4v;
typedef __attribute__((ext_vector_type(4))) float f32x4;
typedef unsigned long long u64;

static __device__ __forceinline__ short f2bf(float f) {
  union { float f; unsigned u; } v; v.f = f;
  unsigned r = (v.u + 0x7fffu + ((v.u >> 16) & 1u)) >> 16;  // RNE
  return (short)r;
}
static __device__ __forceinline__ short8 pack8(f32x4 lo, f32x4 hi) {
  short8 r;
  r[0] = f2bf(lo[0]); r[1] = f2bf(lo[1]); r[2] = f2bf(lo[2]); r[3] = f2bf(lo[3]);
  r[4] = f2bf(hi[0]); r[5] = f2bf(hi[1]); r[6] = f2bf(hi[2]); r[7] = f2bf(hi[3]);
  return r;
}

// ---------------- prepass: W1,W2 fp32 -> bf16 (RNE), 8 elems/thread ----------------
__global__ __launch_bounds__(256)
void convert_w(const float* __restrict__ W1, const float* __restrict__ W2,
               short* __restrict__ W1b, short* __restrict__ W2b)
{
  const size_t NW = (size_t)WID * WID;
  size_t i = ((size_t)blockIdx.x * 256 + threadIdx.x) * 8;
  const float* src = (i < NW) ? (W1 + i) : (W2 + (i - NW));
  short*       dst = (i < NW) ? (W1b + i) : (W2b + (i - NW));
  *(short8*)dst = pack8(*(const f32x4*)src, *(const f32x4*)(src + 4));
}

// ---------------- gemm1: h = |s_t @ W1^T + b1| ----------------
__global__ __launch_bounds__(256, 2)
void gemm1(int t, const float* __restrict__ inp, const short* __restrict__ SbOld,
           const short* __restrict__ W1b, const float* __restrict__ b1f,
           short* __restrict__ hb)
{
  const int tid = threadIdx.x, bid = blockIdx.x;
  const int mt = bid & 3, nt = bid >> 2;     // same-XCD WGs share mt (A slice)
  const int mbase = mt * 32, n0 = nt * 32;
  const int wave = tid >> 6, lane = tid & 63;
  const int l15 = lane & 15, q8 = (lane >> 4) * 8, kb = wave * 512;

  __shared__ float red[4][16][65];

  const int m0 = mbase + l15, m1 = mbase + 16 + l15;
  const short* Bp0 = W1b + (size_t)(n0 + l15) * WID + kb + q8;
  const short* Bp1 = W1b + (size_t)(n0 + 16 + l15) * WID + kb + q8;

  f32x4 a00{}, a01{}, a10{}, a11{};
#pragma unroll
  for (int ks = 0; ks < 16; ++ks) {
    short8 x0, x1;
    bool act = true;
    if (kb == 0 && ks < 2) {                 // k in [0,64): x_t (fp32 -> bf16)
      const float* p0 = inp + ((size_t)t * NB + m0) * 64 + (ks * 32 + q8);
      const float* p1 = inp + ((size_t)t * NB + m1) * 64 + (ks * 32 + q8);
      x0 = pack8(*(const f32x4*)p0, *(const f32x4*)(p0 + 4));
      x1 = pack8(*(const f32x4*)p1, *(const f32x4*)(p1 + 4));
    } else if (t > 0) {                      // k in [64,2048): bf16 state (plain load)
      x0 = *(const short8*)(SbOld + (size_t)m0 * SS + (kb + ks * 32 - 64 + q8));
      x1 = *(const short8*)(SbOld + (size_t)m1 * SS + (kb + ks * 32 - 64 + q8));
    } else act = false;                      // t==0: state is zero
    if (act) {
      short8 b0 = *(const short8*)(Bp0 + ks * 32);
      short8 b1v = *(const short8*)(Bp1 + ks * 32);
      a00 = __builtin_amdgcn_mfma_f32_16x16x32_bf16(x0, b0,  a00, 0, 0, 0);
      a01 = __builtin_amdgcn_mfma_f32_16x16x32_bf16(x0, b1v, a01, 0, 0, 0);
      a10 = __builtin_amdgcn_mfma_f32_16x16x32_bf16(x1, b0,  a10, 0, 0, 0);
      a11 = __builtin_amdgcn_mfma_f32_16x16x32_bf16(x1, b1v, a11, 0, 0, 0);
    }
  }
#pragma unroll
  for (int r = 0; r < 4; ++r) {              // ridx = mtile*8 + ntile*4 + r
    red[wave][r][lane]      = a00[r];
    red[wave][4 + r][lane]  = a01[r];
    red[wave][8 + r][lane]  = a10[r];
    red[wave][12 + r][lane] = a11[r];
  }
  __syncthreads();
  {
    const int o = tid * 4, ml = o >> 5, nl = o & 31;
    const int mrow = mbase + ml;
    short4v hv;
#pragma unroll
    for (int j = 0; j < 4; ++j) {
      const int nn   = nl + j;
      const int lidx = ((ml >> 2) & 3) * 16 + (nn & 15);   // C layout (verified R1-R8)
      const int ridx = (ml >> 4) * 8 + (nn >> 4) * 4 + (ml & 3);
      float s = red[0][ridx][lidx] + red[1][ridx][lidx]
              + red[2][ridx][lidx] + red[3][ridx][lidx] + b1f[n0 + nn];
      hv[j] = f2bf(fabsf(s));
    }
    *(short4v*)(hb + (size_t)mrow * WID + (n0 + nl)) = hv;
  }
}

// ---------------- gemm2: g = h @ W2^T + b2 ; s' = 0.9*shift(s) + 0.1*g ----------------
__global__ __launch_bounds__(256, 2)
void gemm2(int t, const float* __restrict__ inp, const short* __restrict__ hb,
           const short* __restrict__ W2b, const float* __restrict__ b2f,
           const float* __restrict__ SfOld, float* __restrict__ SfNew,
           short* __restrict__ SbNew, float* __restrict__ out)
{
  const int tid = threadIdx.x, bid = blockIdx.x;
  const int mt = bid & 3, nt = bid >> 2;
  const int mbase = mt * 32, n0 = nt * 32;
  const int wave = tid >> 6, lane = tid & 63;
  const int l15 = lane & 15, q8 = (lane >> 4) * 8, kb = wave * 512;

  __shared__ float red[4][16][65];

  const int m0 = mbase + l15, m1 = mbase + 16 + l15;
  const short* Bp0 = W2b + (size_t)(n0 + l15) * WID + kb + q8;
  const short* Bp1 = W2b + (size_t)(n0 + 16 + l15) * WID + kb + q8;
  const short* h0 = hb + (size_t)m0 * WID + kb + q8;
  const short* h1 = hb + (size_t)m1 * WID + kb + q8;

  f32x4 c00{}, c01{}, c10{}, c11{};
#pragma unroll
  for (int ks = 0; ks < 16; ++ks) {
    short8 x0 = *(const short8*)(h0 + ks * 32);
    short8 x1 = *(const short8*)(h1 + ks * 32);
    short8 b0 = *(const short8*)(Bp0 + ks * 32);
    short8 b1v = *(const short8*)(Bp1 + ks * 32);
    c00 = __builtin_amdgcn_mfma_f32_16x16x32_bf16(x0, b0,  c00, 0, 0, 0);
    c01 = __builtin_amdgcn_mfma_f32_16x16x32_bf16(x0, b1v, c01, 0, 0, 0);
    c10 = __builtin_amdgcn_mfma_f32_16x16x32_bf16(x1, b0,  c10, 0, 0, 0);
    c11 = __builtin_amdgcn_mfma_f32_16x16x32_bf16(x1, b1v, c11, 0, 0, 0);
  }
#pragma unroll
  for (int r = 0; r < 4; ++r) {
    red[wave][r][lane]      = c00[r];
    red[wave][4 + r][lane]  = c01[r];
    red[wave][8 + r][lane]  = c10[r];
    red[wave][12 + r][lane] = c11[r];
  }
  __syncthreads();

  const int o = tid * 4, ml = o >> 5, nl = o & 31;
  const int mrow = mbase + ml;
  f32x4 gv;
#pragma unroll
  for (int j = 0; j < 4; ++j) {
    const int nn   = nl + j;
    const int lidx = ((ml >> 2) & 3) * 16 + (nn & 15);
    const int ridx = (ml >> 4) * 8 + (nn >> 4) * 4 + (ml & 3);
    gv[j] = red[0][ridx][lidx] + red[1][ridx][lidx]
          + red[2][ridx][lidx] + red[3][ridx][lidx] + b2f[n0 + nn];
  }
  const int c0 = n0 + nl;
  if (t < NSTEPS - 1) {
    if (n0 < SS) {                           // cols >= SS dropped by the shift
      f32x4 prev;
      if (c0 < 64) {                         // shifted-in x_t (exact fp32)
        prev = *(const f32x4*)(inp + ((size_t)t * NB + mrow) * 64 + c0);
      } else if (t > 0) {                    // fp32 master state
        prev = *(const f32x4*)(SfOld + (size_t)mrow * SS + (c0 - 64));
      } else {
        prev = f32x4{0.f, 0.f, 0.f, 0.f};
      }
      f32x4 sv; short4v sb;
#pragma unroll
      for (int j = 0; j < 4; ++j) {
        float vv = 0.9f * prev[j] + 0.1f * gv[j];
        sv[j] = vv; sb[j] = f2bf(vv);
      }
      *(f32x4*)(SfNew + (size_t)mrow * SS + c0) = sv;
      *(short4v*)(SbNew + (size_t)mrow * SS + c0) = sb;
    }
  } else {
    if (n0 >= SS) {                          // final step: emit out
      f32x4 prev = *(const f32x4*)(SfOld + (size_t)mrow * SS + (c0 - 64));
      f32x4 ov;
#pragma unroll
      for (int j = 0; j < 4; ++j) ov[j] = 0.9f * prev[j] + 0.1f * gv[j];
      *(f32x4*)(out + (size_t)mrow * 64 + (c0 - SS)) = ov;
    }
  }
}

extern "C" void kernel_launch(void* const* d_in, const int* in_sizes, int n_in,
                              void* d_out, int out_size, void* d_ws, size_t ws_size,
                              hipStream_t stream)
{
  (void)in_sizes; (void)n_in; (void)out_size; (void)ws_size;
  const float* inp = (const float*)d_in[0];
  const float* W1  = (const float*)d_in[1];
  const float* b1  = (const float*)d_in[2];
  const float* W2  = (const float*)d_in[3];
  const float* b2  = (const float*)d_in[4];
  float* out = (float*)d_out;
  unsigned char* ws = (unsigned char*)d_ws;

  // ws layout (~19.8 MB): W1b | W2b | Sf0 | Sf1 | Sb0 | Sb1 | hb
  const size_t NW   = (size_t)WID * WID;        // 4 Mi elems
  const size_t SFB  = (size_t)NB * SS * 4;      // 1,015,808 B
  const size_t SBB  = (size_t)NB * SS * 2;      //   507,904 B
  short* W1b = (short*)ws;
  short* W2b = (short*)(ws + NW * 2);
  float* Sf0 = (float*)(ws + NW * 4);
  float* Sf1 = (float*)(ws + NW * 4 + SFB);
  short* Sb0 = (short*)(ws + NW * 4 + 2 * SFB);
  short* Sb1 = (short*)(ws + NW * 4 + 2 * SFB + SBB);
  short* hb  = (short*)(ws + NW * 4 + 2 * SFB + 2 * SBB);

  convert_w<<<dim3(4096), dim3(256), 0, stream>>>(W1, W2, W1b, W2b);

  for (int t = 0; t < NSTEPS; ++t) {
    const int w = t & 1;
    float* SfNew = w ? Sf1 : Sf0;  const float* SfOld = w ? Sf0 : Sf1;
    short* SbNew = w ? Sb1 : Sb0;  const short* SbOld = w ? Sb0 : Sb1;
    gemm1<<<dim3(256), dim3(256), 0, stream>>>(t, inp, SbOld, W1b, b1, hb);
    gemm2<<<dim3(256), dim3(256), 0, stream>>>(t, inp, hb, W2b, b2,
                                               SfOld, SfNew, SbNew, out);
  }
}